// Round 1
// baseline (241.449 us; speedup 1.0000x reference)
//
#include <hip/hip_runtime.h>
#include <hip/hip_bf16.h>

#define NN 100000
#define CC 128
#define KK 32
#define BB 64

// ---------------------------------------------------------------------------
// Kernel Z: zero the pooled-output region of d_out (harness poisons 0xAA).
// ---------------------------------------------------------------------------
__global__ __launch_bounds__(256) void hp_zero_out(float* __restrict__ out) {
    int idx = (blockIdx.x * 256 + threadIdx.x) * 4;
    if (idx < BB * KK * CC) {
        float4 z = make_float4(0.f, 0.f, 0.f, 0.f);
        *(float4*)(out + idx) = z;
    }
}

// ---------------------------------------------------------------------------
// Kernel A: fused  h = relu(x@W1+b1);  s = softmax(h@W2+b2)  -> write s.
// One block = 32 nodes. 256 threads.
//   phase 1: thread computes 4 nodes x 4 channels of H (16 acc, 2048 FMA).
//   phase 2: thread computes 4 logits for one node (n = t>>3, k0 = (t&7)*4).
//   phase 3: softmax across 8 lanes via shfl_xor; coalesced float4 s store.
// LDS: xT 16K + W1t 16.5K + Hs 16.5K + W2s 18K = 67K -> 2 blocks/CU.
// ---------------------------------------------------------------------------
__global__ __launch_bounds__(256, 2) void hp_mlp_softmax(
    const float* __restrict__ x,
    const float* __restrict__ W1,
    const float* __restrict__ b1,
    const float* __restrict__ W2,
    const float* __restrict__ b2,
    float* __restrict__ s_out)
{
    __shared__ float xT[CC][32];     // [c][node]; write bank = node -> conflict-free
    __shared__ float W1t[32][132];   // [j in tile][c], +4 pad breaks write conflicts
    __shared__ float Hs[32][132];    // [node][c], +4 pad -> phase-2 reads spread banks
    __shared__ float W2s[CC][36];    // [c][k], +4 pad

    const int t = threadIdx.x;
    const int gbase = blockIdx.x * 32;

    // ---- stage x transposed: thread loads 16 contiguous ch of one node ----
    {
        const int n  = t & 31;
        const int c0 = (t >> 5) * 16;
        const float* xp = x + (size_t)(gbase + n) * CC + c0;
        float4 v0 = *(const float4*)(xp + 0);
        float4 v1 = *(const float4*)(xp + 4);
        float4 v2 = *(const float4*)(xp + 8);
        float4 v3 = *(const float4*)(xp + 12);
        xT[c0 +  0][n] = v0.x; xT[c0 +  1][n] = v0.y; xT[c0 +  2][n] = v0.z; xT[c0 +  3][n] = v0.w;
        xT[c0 +  4][n] = v1.x; xT[c0 +  5][n] = v1.y; xT[c0 +  6][n] = v1.z; xT[c0 +  7][n] = v1.w;
        xT[c0 +  8][n] = v2.x; xT[c0 +  9][n] = v2.y; xT[c0 + 10][n] = v2.z; xT[c0 + 11][n] = v2.w;
        xT[c0 + 12][n] = v3.x; xT[c0 + 13][n] = v3.y; xT[c0 + 14][n] = v3.z; xT[c0 + 15][n] = v3.w;
    }
    // ---- stage W2 ----
    {
        const int r  = t >> 1;
        const int k0 = (t & 1) * 16;
        const float* wp = W2 + r * KK + k0;
        float4 a0 = *(const float4*)(wp + 0);
        float4 a1 = *(const float4*)(wp + 4);
        float4 a2 = *(const float4*)(wp + 8);
        float4 a3 = *(const float4*)(wp + 12);
        *(float4*)&W2s[r][k0 +  0] = a0;
        *(float4*)&W2s[r][k0 +  4] = a1;
        *(float4*)&W2s[r][k0 +  8] = a2;
        *(float4*)&W2s[r][k0 + 12] = a3;
    }
    __syncthreads();

    // ---- phase 1: H tile, 4 nodes x 4 channels per thread ----
    const int n0 = (t & 7) * 4;
    const int c0 = (t >> 3) * 4;
    float acc[4][4] = {{0.f}};

    for (int jt = 0; jt < 4; ++jt) {
        // stage W1 j-tile (issue global loads before the barrier)
        const int r  = t >> 3;
        const int cw = (t & 7) * 16;
        const float* wp = W1 + (size_t)(jt * 32 + r) * CC + cw;
        float4 a0 = *(const float4*)(wp + 0);
        float4 a1 = *(const float4*)(wp + 4);
        float4 a2 = *(const float4*)(wp + 8);
        float4 a3 = *(const float4*)(wp + 12);
        __syncthreads();   // previous tile fully consumed
        *(float4*)&W1t[r][cw +  0] = a0;
        *(float4*)&W1t[r][cw +  4] = a1;
        *(float4*)&W1t[r][cw +  8] = a2;
        *(float4*)&W1t[r][cw + 12] = a3;
        __syncthreads();

        #pragma unroll
        for (int jj = 0; jj < 32; ++jj) {
            const float4 xv = *(const float4*)&xT[jt * 32 + jj][n0];
            const float4 wv = *(const float4*)&W1t[jj][c0];
            acc[0][0] += xv.x * wv.x; acc[0][1] += xv.x * wv.y; acc[0][2] += xv.x * wv.z; acc[0][3] += xv.x * wv.w;
            acc[1][0] += xv.y * wv.x; acc[1][1] += xv.y * wv.y; acc[1][2] += xv.y * wv.z; acc[1][3] += xv.y * wv.w;
            acc[2][0] += xv.z * wv.x; acc[2][1] += xv.z * wv.y; acc[2][2] += xv.z * wv.z; acc[2][3] += xv.z * wv.w;
            acc[3][0] += xv.w * wv.x; acc[3][1] += xv.w * wv.y; acc[3][2] += xv.w * wv.z; acc[3][3] += xv.w * wv.w;
        }
    }

    // bias + ReLU -> Hs
    {
        const float4 bv = *(const float4*)(b1 + c0);
        #pragma unroll
        for (int a = 0; a < 4; ++a) {
            float4 h;
            h.x = fmaxf(acc[a][0] + bv.x, 0.f);
            h.y = fmaxf(acc[a][1] + bv.y, 0.f);
            h.z = fmaxf(acc[a][2] + bv.z, 0.f);
            h.w = fmaxf(acc[a][3] + bv.w, 0.f);
            *(float4*)&Hs[n0 + a][c0] = h;
        }
    }
    __syncthreads();

    // ---- phase 2: logits for node pn, k in [pk, pk+4) ----
    const int pn = t >> 3;
    const int pk = (t & 7) * 4;
    float4 l = *(const float4*)(b2 + pk);
    #pragma unroll 8
    for (int c = 0; c < CC; ++c) {
        const float hv = Hs[pn][c];
        const float4 wv = *(const float4*)&W2s[c][pk];
        l.x += hv * wv.x; l.y += hv * wv.y; l.z += hv * wv.z; l.w += hv * wv.w;
    }

    // ---- phase 3: softmax across the 8 lanes holding this node ----
    float m = fmaxf(fmaxf(l.x, l.y), fmaxf(l.z, l.w));
    m = fmaxf(m, __shfl_xor(m, 1));
    m = fmaxf(m, __shfl_xor(m, 2));
    m = fmaxf(m, __shfl_xor(m, 4));
    const float e0 = __expf(l.x - m);
    const float e1 = __expf(l.y - m);
    const float e2 = __expf(l.z - m);
    const float e3 = __expf(l.w - m);
    float ssum = e0 + e1 + e2 + e3;
    ssum += __shfl_xor(ssum, 1);
    ssum += __shfl_xor(ssum, 2);
    ssum += __shfl_xor(ssum, 4);
    const float inv = 1.f / ssum;
    float4 sv = make_float4(e0 * inv, e1 * inv, e2 * inv, e3 * inv);
    *(float4*)(s_out + (size_t)(gbase + pn) * KK + pk) = sv;
}

// ---------------------------------------------------------------------------
// Kernel B: out[b,k,c] += s[n,k] * x[n,c]  segment-summed over sorted batch.
// 256 nodes/block; thread owns a 4k x 4c register tile of the [32,128]
// per-graph accumulator; flush by atomicAdd only on (uniform) graph change.
// ---------------------------------------------------------------------------
__global__ __launch_bounds__(256) void hp_scatter(
    const float* __restrict__ x,
    const int* __restrict__ batch,
    const float* __restrict__ s,
    float* __restrict__ out)
{
    __shared__ float xs[8][CC];
    __shared__ float ss[8][KK];
    __shared__ int   bs[8];

    const int t = threadIdx.x;
    const int start = blockIdx.x * 256;
    const int end = min(start + 256, NN);

    const int c0 = (t & 31) * 4;
    const int k0 = (t >> 5) * 4;
    float acc[4][4] = {{0.f}};
    int cur = -1;

    for (int g = 0; g < 32; ++g) {
        const int nb = start + g * 8;
        if (nb >= end) break;
        const int gcnt = min(8, end - nb);
        __syncthreads();   // previous panel fully consumed
        {
            const int i = t >> 5;
            if (i < gcnt) {
                float4 v = *(const float4*)(x + (size_t)(nb + i) * CC + (t & 31) * 4);
                *(float4*)&xs[i][(t & 31) * 4] = v;
            }
            if (t < gcnt * KK)
                ss[t >> 5][t & 31] = s[(size_t)(nb + (t >> 5)) * KK + (t & 31)];
            if (t < gcnt)
                bs[t] = batch[nb + t];
        }
        __syncthreads();

        for (int i = 0; i < gcnt; ++i) {
            const int bg = bs[i];              // uniform across block
            if (bg != cur) {
                if (cur >= 0) {
                    float* op = out + (size_t)cur * KK * CC;
                    #pragma unroll
                    for (int a = 0; a < 4; ++a) {
                        #pragma unroll
                        for (int q = 0; q < 4; ++q) {
                            atomicAdd(op + (k0 + a) * CC + c0 + q, acc[a][q]);
                            acc[a][q] = 0.f;
                        }
                    }
                }
                cur = bg;
            }
            const float4 xv = *(const float4*)&xs[i][c0];
            const float4 sv = *(const float4*)&ss[i][k0];
            acc[0][0] += sv.x * xv.x; acc[0][1] += sv.x * xv.y; acc[0][2] += sv.x * xv.z; acc[0][3] += sv.x * xv.w;
            acc[1][0] += sv.y * xv.x; acc[1][1] += sv.y * xv.y; acc[1][2] += sv.y * xv.z; acc[1][3] += sv.y * xv.w;
            acc[2][0] += sv.z * xv.x; acc[2][1] += sv.z * xv.y; acc[2][2] += sv.z * xv.z; acc[2][3] += sv.z * xv.w;
            acc[3][0] += sv.w * xv.x; acc[3][1] += sv.w * xv.y; acc[3][2] += sv.w * xv.z; acc[3][3] += sv.w * xv.w;
        }
    }
    if (cur >= 0) {
        float* op = out + (size_t)cur * KK * CC;
        #pragma unroll
        for (int a = 0; a < 4; ++a) {
            #pragma unroll
            for (int q = 0; q < 4; ++q)
                atomicAdd(op + (k0 + a) * CC + c0 + q, acc[a][q]);
        }
    }
}

// ---------------------------------------------------------------------------
extern "C" void kernel_launch(void* const* d_in, const int* in_sizes, int n_in,
                              void* d_out, int out_size, void* d_ws, size_t ws_size,
                              hipStream_t stream) {
    const float* x     = (const float*)d_in[0];
    const int*   batch = (const int*)d_in[1];
    const float* W1    = (const float*)d_in[2];
    const float* b1    = (const float*)d_in[3];
    const float* W2    = (const float*)d_in[4];
    const float* b2    = (const float*)d_in[5];

    float* out = (float*)d_out;                    // [B,K,C] = 262144 floats
    float* s   = out + (size_t)BB * KK * CC;       // [N,K]   = 3200000 floats

    hp_zero_out<<<(BB * KK * CC) / (256 * 4), 256, 0, stream>>>(out);
    hp_mlp_softmax<<<NN / 32, 256, 0, stream>>>(x, W1, b1, W2, b2, s);
    hp_scatter<<<(NN + 255) / 256, 256, 0, stream>>>(x, batch, s, out);
}